// Round 3
// baseline (2002.040 us; speedup 1.0000x reference)
//
#include <hip/hip_runtime.h>
#include <math.h>

#define T_STEPS 8192
#define NB 16

// hardware transcendentals (v_exp_f32 = 2^x, v_log_f32 = log2 x)
__device__ __forceinline__ float hw_exp2(float x) { return __builtin_amdgcn_exp2f(x); }
__device__ __forceinline__ float hw_log2(float x) { return __builtin_amdgcn_logf(x); }

// ---------------------------------------------------------------------------
// Kernel 1: sequential FUSE scan. One thread per (ensemble, band).
// 16 blocks x 64 threads: each wave handles 4 ensembles (16 lanes each) and
// runs alone on its CU. Per-ensemble reductions via 16-lane shfl_xor butterfly.
// ---------------------------------------------------------------------------
__global__ __launch_bounds__(64) void fuse_scan_kernel(
    const float* __restrict__ raw,        // [64][29]
    const float* __restrict__ forcing,    // [8192][3]
    const float* __restrict__ state_init, // [2]
    const float* __restrict__ area_frac,  // [16]
    const float* __restrict__ mean_elev,  // [16]
    float* __restrict__ runoff)           // [64][8192]
{
    const int lane = threadIdx.x;   // 0..63
    const int grp  = lane >> 4;     // 0..3   (ensemble within wave)
    const int nb   = lane & 15;     // band
    const int e    = blockIdx.x * 4 + grp;

    const float* rp = raw + e * 29;
    auto phys = [&](int idx, float lo, float hi) {
        float x = rp[idx];
        float s = 1.0f / (1.0f + expf(-x));
        return lo + (hi - lo) * s;
    };
    const float s1max = phys(0,  50.0f,  5000.0f);
    const float s2max = phys(1,  100.0f, 10000.0f);
    const float ku    = phys(6,  0.01f,  1000.0f);
    const float c_exp = phys(7,  1.0f,   20.0f);
    const float ki    = phys(11, 0.01f,  1000.0f);
    const float ks    = phys(12, 0.001f, 10000.0f);
    const float n_exp = phys(13, 1.0f,   10.0f);
    const float acmax = phys(17, 0.05f,  0.95f);
    const float b_exp = phys(18, 0.001f, 3.0f);
    const float train = phys(22, -2.0f,  4.0f);
    const float tmelt = phys(23, -2.0f,  4.0f);
    const float mrate = phys(24, 1.0f,   10.0f);
    const float lapse = phys(25, -9.8f,  0.0f);
    const float opg   = phys(26, 0.0f,   1.0f);

    const float delev  = (mean_elev[nb] - 1500.0f) * 0.001f;
    const float tshift = lapse * delev;
    const float pmult  = fmaxf(1.0f + opg * delev, 0.0f);
    const float af     = area_frac[nb];

    const float inv_s1max = 1.0f / s1max;
    const float inv_s2max = 1.0f / s2max;

    float swe = 0.0f;
    float s1  = state_init[0];   // 50
    float s2  = state_init[1];   // 250 (replicated per-lane, stays identical)

    float* __restrict__ out = runoff + (size_t)e * T_STEPS;

    for (int t0 = 0; t0 < T_STEPS; t0 += 4) {
        // forcing is [T][3]; 4 steps = 12 floats = 3 aligned float4 loads
        const float4 f0 = *(const float4*)(forcing + 3 * t0);
        const float4 f1 = *(const float4*)(forcing + 3 * t0 + 4);
        const float4 f2 = *(const float4*)(forcing + 3 * t0 + 8);
        const float P [4] = { f0.x, f0.w, f1.z, f2.y };
        const float PE[4] = { f0.y, f1.x, f1.w, f2.z };
        const float TA[4] = { f0.z, f1.y, f2.x, f2.w };

        #pragma unroll
        for (int k = 0; k < 4; ++k) {
            const float p = P[k], pet = PE[k], tair = TA[k];

            // snow bucket
            const float tb   = tair + tshift;
            const float pb   = p * pmult;
            const float rain = (tb > train) ? pb : 0.0f;
            const float snow = pb - rain;
            const float ssn  = swe + snow;
            const float melt = fminf(mrate * fmaxf(tb - tmelt, 0.0f), ssn);
            swe = ssn - melt;
            const float infl = rain + melt;

            // upper bucket
            const float w1  = fminf(fmaxf(s1 * inv_s1max, 0.0f), 1.0f);
            const float lg  = hw_log2(w1);
            const float pwb = hw_exp2(b_exp * lg);   // w1^b
            const float pwc = hw_exp2(c_exp * lg);   // w1^c
            const float evap = pet * w1;
            const float qsx  = acmax * pwb * infl;
            const float perc = ku * pwc;
            const float qif  = ki * w1;
            const float s1n  = s1 + infl - qsx - evap - perc - qif;
            const float over1 = fmaxf(s1n - s1max, 0.0f);
            s1 = fminf(fmaxf(s1n, 0.0f), s1max);
            const float qsurf = qsx + over1;

            // per-ensemble reductions over the 16 bands
            float r1 = af * perc;            // -> rech
            float r2 = af * (qsurf + qif);   // -> surface part of q
            #pragma unroll
            for (int off = 8; off; off >>= 1) {
                r1 += __shfl_xor(r1, off, 16);
                r2 += __shfl_xor(r2, off, 16);
            }

            // lower bucket (replicated across the 16 lanes of the group)
            const float w2  = fminf(fmaxf(s2 * inv_s2max, 0.0f), 1.0f);
            const float qb  = ks * hw_exp2(n_exp * hw_log2(w2));  // ks*w2^n
            const float s2n = s2 + r1 - qb;
            const float over2 = fmaxf(s2n - s2max, 0.0f);
            s2 = fminf(fmaxf(s2n, 0.0f), s2max);

            const float q = r2 + qb + over2;
            if (nb == 0) out[t0 + k] = q;
        }
    }
}

// ---------------------------------------------------------------------------
// Kernel 2: gamma unit-hydrograph routing (30-tap causal FIR along time).
// One block per ensemble; runoff row staged in LDS.
// ---------------------------------------------------------------------------
__global__ __launch_bounds__(256) void route_kernel(
    const float* __restrict__ raw,     // [64][29]
    const float* __restrict__ runoff,  // [64][8192]
    float* __restrict__ routed)        // [64][8192]
{
    __shared__ float w_sh[32];
    __shared__ float row[T_STEPS];     // 32 KB

    const int e   = blockIdx.x;
    const int tid = threadIdx.x;

    // stage the runoff row (coalesced float4)
    const float4* src  = (const float4*)(runoff + (size_t)e * T_STEPS);
    float4*       dst4 = (float4*)row;
    for (int i = tid; i < T_STEPS / 4; i += 256) dst4[i] = src[i];

    // gamma UH weights (UH_LEN=30, shape k=2.5)
    if (tid < 32) {
        float x     = raw[e * 29 + 21];                 // mu_t raw
        float sig   = 1.0f / (1.0f + expf(-x));
        float delay = 0.01f + (5.0f - 0.01f) * sig;
        float wv = 0.0f;
        if (tid < 30) {
            const float tm   = (float)tid + 0.5f;
            const float kk   = 2.5f;
            const float lgam = 0.28468287047291918f;    // lgamma(2.5)
            float lp = (kk - 1.0f) * logf(tm) - tm / delay - lgam - kk * logf(delay);
            wv = expf(lp);
        }
        w_sh[tid] = wv;
    }
    __syncthreads();
    if (tid == 0) {
        float s = 0.0f;
        for (int l = 0; l < 30; ++l) s += w_sh[l];
        w_sh[31] = 1.0f / s;
    }
    __syncthreads();

    float wloc[30];
    const float inv = w_sh[31];
    #pragma unroll
    for (int l = 0; l < 30; ++l) wloc[l] = w_sh[l] * inv;

    float* __restrict__ out = routed + (size_t)e * T_STEPS;
    for (int t = tid; t < T_STEPS; t += 256) {
        float acc = 0.0f;
        #pragma unroll
        for (int l = 0; l < 30; ++l) {
            const int idx = t - l;
            const float v = (idx >= 0) ? row[idx] : 0.0f;
            acc = fmaf(wloc[l], v, acc);
        }
        out[t] = acc;
    }
}

// ---------------------------------------------------------------------------
extern "C" void kernel_launch(void* const* d_in, const int* in_sizes, int n_in,
                              void* d_out, int out_size, void* d_ws, size_t ws_size,
                              hipStream_t stream) {
    const float* raw        = (const float*)d_in[0];   // (64, 29)
    const float* forcing    = (const float*)d_in[1];   // (8192, 3)
    const float* state_init = (const float*)d_in[2];   // (2,)
    const float* area_frac  = (const float*)d_in[3];   // (16,)
    const float* mean_elev  = (const float*)d_in[4];   // (16,)

    float* routed = (float*)d_out;                     // (64, 8192)
    float* runoff = (float*)d_ws;                      // 2 MB scratch

    fuse_scan_kernel<<<16, 64, 0, stream>>>(raw, forcing, state_init,
                                            area_frac, mean_elev, runoff);
    route_kernel<<<64, 256, 0, stream>>>(raw, runoff, routed);
}

// Round 4
// 929.171 us; speedup vs baseline: 2.1547x; 2.1547x over previous
//
#include <hip/hip_runtime.h>
#include <math.h>

#define T_STEPS 8192

// hardware transcendentals (v_exp_f32 = 2^x, v_log_f32 = log2 x)
__device__ __forceinline__ float hw_exp2(float x) { return __builtin_amdgcn_exp2f(x); }
__device__ __forceinline__ float hw_log2(float x) { return __builtin_amdgcn_logf(x); }

// DPP-based add of a rotated copy (within 16-lane rows). CTRL = 0x120|n (row_ror:n).
template<int CTRL>
__device__ __forceinline__ float dpp_add(float x) {
    int y = __builtin_amdgcn_update_dpp(0, __float_as_int(x), CTRL, 0xF, 0xF, true);
    return x + __int_as_float(y);
}
// Sum across a 16-lane row; every lane ends with the full sum (rotation butterfly).
__device__ __forceinline__ float row16_sum(float x) {
    x = dpp_add<0x128>(x);   // ror:8
    x = dpp_add<0x124>(x);   // ror:4
    x = dpp_add<0x122>(x);   // ror:2
    x = dpp_add<0x121>(x);   // ror:1
    return x;
}

// ---------------------------------------------------------------------------
// Kernel 1: sequential FUSE scan. One thread per (ensemble, band).
// 16 blocks x 64 threads; each 16-lane DPP row = one ensemble's 16 bands.
// Reductions are pure-VALU (DPP), so the loop has zero LDS ops.
// ---------------------------------------------------------------------------
__global__ __launch_bounds__(64) void fuse_scan_kernel(
    const float* __restrict__ raw,        // [64][29]
    const float* __restrict__ forcing,    // [8192][3]
    const float* __restrict__ state_init, // [2]
    const float* __restrict__ area_frac,  // [16]
    const float* __restrict__ mean_elev,  // [16]
    float* __restrict__ runoff)           // [64][8192]
{
    const int lane = threadIdx.x;   // 0..63
    const int grp  = lane >> 4;     // ensemble within wave
    const int nb   = lane & 15;     // band
    const int e    = blockIdx.x * 4 + grp;

    const float* rp = raw + e * 29;
    auto phys = [&](int idx, float lo, float hi) {
        float x = rp[idx];
        float s = 1.0f / (1.0f + expf(-x));
        return lo + (hi - lo) * s;
    };
    const float s1max = phys(0,  50.0f,  5000.0f);
    const float s2max = phys(1,  100.0f, 10000.0f);
    const float ku    = phys(6,  0.01f,  1000.0f);
    const float c_exp = phys(7,  1.0f,   20.0f);
    const float ki    = phys(11, 0.01f,  1000.0f);
    const float ks    = phys(12, 0.001f, 10000.0f);
    const float n_exp = phys(13, 1.0f,   10.0f);
    const float acmax = phys(17, 0.05f,  0.95f);
    const float b_exp = phys(18, 0.001f, 3.0f);
    const float train = phys(22, -2.0f,  4.0f);
    const float tmelt = phys(23, -2.0f,  4.0f);
    const float mrate = phys(24, 1.0f,   10.0f);
    const float lapse = phys(25, -9.8f,  0.0f);
    const float opg   = phys(26, 0.0f,   1.0f);

    const float delev  = (mean_elev[nb] - 1500.0f) * 0.001f;
    const float tshift = lapse * delev;
    const float pmult  = fmaxf(1.0f + opg * delev, 0.0f);
    const float af     = area_frac[nb];

    const float inv_s1max = 1.0f / s1max;
    const float inv_s2max = 1.0f / s2max;

    float swe = 0.0f;
    float s1  = state_init[0];   // 50   (<= s1max always; invariant s1 in [0,s1max])
    float s2  = state_init[1];   // 250  (may exceed s2max -> keep upper clip on w2)
    float qkeep = 0.0f;

    float* __restrict__ out = runoff + (size_t)e * T_STEPS;

    // prefetch steps 0..3
    float4 c0 = *(const float4*)(forcing + 0);
    float4 c1 = *(const float4*)(forcing + 4);
    float4 c2 = *(const float4*)(forcing + 8);

    for (int t0 = 0; t0 < T_STEPS; t0 += 16) {
        #pragma unroll
        for (int tt = 0; tt < 16; tt += 4) {
            // prefetch the next 4-step chunk (clamped at the tail)
            int tn = t0 + tt + 4;
            tn = (tn > T_STEPS - 4) ? (T_STEPS - 4) : tn;
            const float4 n0 = *(const float4*)(forcing + 3 * tn);
            const float4 n1 = *(const float4*)(forcing + 3 * tn + 4);
            const float4 n2 = *(const float4*)(forcing + 3 * tn + 8);

            const float P [4] = { c0.x, c0.w, c1.z, c2.y };
            const float PE[4] = { c0.y, c1.x, c1.w, c2.z };
            const float TA[4] = { c0.z, c1.y, c2.x, c2.w };

            #pragma unroll
            for (int k = 0; k < 4; ++k) {
                const float p = P[k], pet = PE[k], tair = TA[k];

                // snow bucket
                const float tb   = tair + tshift;
                const float pb   = p * pmult;
                const float rain = (tb > train) ? pb : 0.0f;
                const float snow = pb - rain;
                const float ssn  = swe + snow;
                const float melt = fminf(mrate * fmaxf(tb - tmelt, 0.0f), ssn);
                swe = ssn - melt;
                const float infl = rain + melt;

                // upper bucket (w1 in [0,1] by invariant; log2(0)=-inf -> pow=0, OK)
                const float w1   = s1 * inv_s1max;
                const float lg   = hw_log2(w1);
                const float pwb  = hw_exp2(b_exp * lg);   // w1^b
                const float pwc  = hw_exp2(c_exp * lg);   // w1^c
                const float perc = ku * pwc;
                const float qif  = ki * w1;
                const float qsx  = (acmax * infl) * pwb;
                const float s1n  = s1 + infl - pet * w1 - qif - perc - qsx;
                const float sHi  = fminf(s1n, s1max);
                const float over1 = s1n - sHi;            // = max(s1n - s1max, 0)
                s1 = fmaxf(sHi, 0.0f);
                const float qsurf = qsx + over1;

                // per-ensemble sums over 16 bands (pure-VALU DPP butterfly)
                const float r1 = row16_sum(af * perc);           // rech
                const float r2 = row16_sum(af * (qsurf + qif));  // surface q

                // lower bucket (replicated identically across the row)
                const float w2   = fminf(s2 * inv_s2max, 1.0f);
                const float qb   = ks * hw_exp2(n_exp * hw_log2(w2));
                const float s2n  = s2 + r1 - qb;
                const float s2Hi = fminf(s2n, s2max);
                const float over2 = s2n - s2Hi;
                s2 = fmaxf(s2Hi, 0.0f);

                const float q = r2 + qb + over2;
                // lane nb keeps step (t0 + nb)'s q
                qkeep = ((tt + k) == nb) ? q : qkeep;
            }
            c0 = n0; c1 = n1; c2 = n2;
        }
        // one coalesced store per 16 steps: lanes of a group cover 16 consecutive t
        out[t0 + nb] = qkeep;
    }
}

// ---------------------------------------------------------------------------
// Kernel 2: gamma unit-hydrograph routing (30-tap causal FIR along time).
// ---------------------------------------------------------------------------
__global__ __launch_bounds__(256) void route_kernel(
    const float* __restrict__ raw,     // [64][29]
    const float* __restrict__ runoff,  // [64][8192]
    float* __restrict__ routed)        // [64][8192]
{
    __shared__ float w_sh[32];
    __shared__ float row[T_STEPS];     // 32 KB

    const int e   = blockIdx.x;
    const int tid = threadIdx.x;

    const float4* src  = (const float4*)(runoff + (size_t)e * T_STEPS);
    float4*       dst4 = (float4*)row;
    for (int i = tid; i < T_STEPS / 4; i += 256) dst4[i] = src[i];

    if (tid < 32) {
        float x     = raw[e * 29 + 21];                 // mu_t raw
        float sig   = 1.0f / (1.0f + expf(-x));
        float delay = 0.01f + (5.0f - 0.01f) * sig;
        float wv = 0.0f;
        if (tid < 30) {
            const float tm   = (float)tid + 0.5f;
            const float kk   = 2.5f;
            const float lgam = 0.28468287047291918f;    // lgamma(2.5)
            float lp = (kk - 1.0f) * logf(tm) - tm / delay - lgam - kk * logf(delay);
            wv = expf(lp);
        }
        w_sh[tid] = wv;
    }
    __syncthreads();
    if (tid == 0) {
        float s = 0.0f;
        for (int l = 0; l < 30; ++l) s += w_sh[l];
        w_sh[31] = 1.0f / s;
    }
    __syncthreads();

    float wloc[30];
    const float inv = w_sh[31];
    #pragma unroll
    for (int l = 0; l < 30; ++l) wloc[l] = w_sh[l] * inv;

    float* __restrict__ out = routed + (size_t)e * T_STEPS;
    for (int t = tid; t < T_STEPS; t += 256) {
        float acc = 0.0f;
        #pragma unroll
        for (int l = 0; l < 30; ++l) {
            const int idx = t - l;
            const float v = (idx >= 0) ? row[idx] : 0.0f;
            acc = fmaf(wloc[l], v, acc);
        }
        out[t] = acc;
    }
}

// ---------------------------------------------------------------------------
extern "C" void kernel_launch(void* const* d_in, const int* in_sizes, int n_in,
                              void* d_out, int out_size, void* d_ws, size_t ws_size,
                              hipStream_t stream) {
    const float* raw        = (const float*)d_in[0];   // (64, 29)
    const float* forcing    = (const float*)d_in[1];   // (8192, 3)
    const float* state_init = (const float*)d_in[2];   // (2,)
    const float* area_frac  = (const float*)d_in[3];   // (16,)
    const float* mean_elev  = (const float*)d_in[4];   // (16,)

    float* routed = (float*)d_out;                     // (64, 8192)
    float* runoff = (float*)d_ws;                      // 2 MB scratch

    fuse_scan_kernel<<<16, 64, 0, stream>>>(raw, forcing, state_init,
                                            area_frac, mean_elev, runoff);
    route_kernel<<<64, 256, 0, stream>>>(raw, runoff, routed);
}